// Round 11
// baseline (130.864 us; speedup 1.0000x reference)
//
#include <hip/hip_runtime.h>
#include <hip/hip_bf16.h>
#include <stdint.h>

#define S_LEN 2048
#define DM    1024
#define NH    16
#define DK    64
#define NBATCH 2

typedef __attribute__((ext_vector_type(8))) short bf8_t;   // 8 bf16 (4 VGPRs)
typedef __attribute__((ext_vector_type(4))) short s4_t;    // 4 bf16 (8B)
typedef __attribute__((ext_vector_type(4))) float f4_t;    // MFMA accum

using bf16 = __hip_bfloat16;

#define NEG_BIG (-1.0e30f)
#define SCALE2  (0.125f * 1.44269504088896f)   // 1/sqrt(dk) * log2(e)

static __device__ __forceinline__ f4_t mfma16(bf8_t a, bf8_t b, f4_t c) {
    return __builtin_amdgcn_mfma_f32_16x16x32_bf16(a, b, c, 0, 0, 0);
}

static __device__ __forceinline__ short f2b(float f) {
    __hip_bfloat16 h = __float2bfloat16(f);
    return *reinterpret_cast<short*>(&h);
}

// async global->LDS, 16B per lane. Dest must be linear: uniform base + lane*16.
static __device__ __forceinline__ void g2l16(const bf16* g, bf16* l) {
#if __has_builtin(__builtin_amdgcn_global_load_lds)
    __builtin_amdgcn_global_load_lds(
        (const __attribute__((address_space(1))) void*)g,
        (__attribute__((address_space(3))) void*)l, 16, 0, 0);
#else
    *(bf8_t*)l = *(const bf8_t*)g;   // correct, slower
#endif
}

// ---------------------------------------------------------------------------
// fp32 -> bf16 pre-convert: ob = [xb 4M | wqb 1M | wkb 1M | wvb 1M | wob 1M]
// ---------------------------------------------------------------------------
__global__ __launch_bounds__(256)
void cvt_all(const float* __restrict__ x,  const float* __restrict__ wq,
             const float* __restrict__ wk, const float* __restrict__ wv,
             const float* __restrict__ wo, bf16* __restrict__ ob) {
    const size_t SEG = 1u << 20;
    size_t i = ((size_t)blockIdx.x * 256 + threadIdx.x) * 8;
    const float* src;
    if      (i < 4 * SEG) src = x  + i;
    else if (i < 5 * SEG) src = wq + (i - 4 * SEG);
    else if (i < 6 * SEG) src = wk + (i - 5 * SEG);
    else if (i < 7 * SEG) src = wv + (i - 6 * SEG);
    else                  src = wo + (i - 7 * SEG);
    float4 f0 = *(const float4*)(src);
    float4 f1 = *(const float4*)(src + 4);
    bf8_t v;
    v[0]=f2b(f0.x); v[1]=f2b(f0.y); v[2]=f2b(f0.z); v[3]=f2b(f0.w);
    v[4]=f2b(f1.x); v[5]=f2b(f1.y); v[6]=f2b(f1.z); v[7]=f2b(f1.w);
    *(bf8_t*)(ob + i) = v;
}

// ---------------------------------------------------------------------------
// bf16 GEMM main loop (m97 structure): 128x128 tile, BK=32, LINEAR LDS,
// global_load_lds width-16 staging, 4 waves 2x2, 4x4 16x16 frags.
// ---------------------------------------------------------------------------
#define GEMM_B_MAINLOOP(Aptr, Bptr)                                          \
    __shared__ bf16 As[128][32];                                             \
    __shared__ bf16 Bs[128][32];                                             \
    const int tid  = threadIdx.x;                                            \
    const int lane = tid & 63;                                               \
    const int w    = tid >> 6;                                               \
    const int wr   = w >> 1, wc = w & 1;                                     \
    const int lhi  = lane >> 4, llo = lane & 15;                             \
    const int bm   = blockIdx.x * 128;                                       \
    const int bn   = blockIdx.y * 128;                                       \
    const int r0c  = tid >> 2;                 /* chunk row, t=0 */          \
    const int c0c  = (tid & 3) << 3;           /* chunk col      */          \
    const int r1c  = (256 + tid) >> 2;                                       \
    f4_t acc[4][4] = {};                                                     \
    for (int k0 = 0; k0 < 1024; k0 += 32) {                                  \
        __syncthreads();                                                     \
        g2l16(Aptr + (size_t)(bm + r0c) * 1024 + k0 + c0c,                   \
              &As[0][0] + (size_t)tid * 8);                                  \
        g2l16(Aptr + (size_t)(bm + r1c) * 1024 + k0 + c0c,                   \
              &As[0][0] + (size_t)(256 + tid) * 8);                          \
        g2l16(Bptr + (size_t)(bn + r0c) * 1024 + k0 + c0c,                   \
              &Bs[0][0] + (size_t)tid * 8);                                  \
        g2l16(Bptr + (size_t)(bn + r1c) * 1024 + k0 + c0c,                   \
              &Bs[0][0] + (size_t)(256 + tid) * 8);                          \
        asm volatile("s_waitcnt vmcnt(0)" ::: "memory");                     \
        __syncthreads();                                                     \
        bf8_t af[4], bfr[4];                                                 \
        _Pragma("unroll")                                                    \
        for (int i = 0; i < 4; ++i) {                                        \
            af[i]  = *(const bf8_t*)(&As[wr * 64 + i * 16 + llo][lhi * 8]);  \
            bfr[i] = *(const bf8_t*)(&Bs[wc * 64 + i * 16 + llo][lhi * 8]);  \
        }                                                                    \
        _Pragma("unroll")                                                    \
        for (int mi = 0; mi < 4; ++mi)                                       \
            _Pragma("unroll")                                                \
            for (int ni = 0; ni < 4; ++ni)                                   \
                acc[mi][ni] = mfma16(af[mi], bfr[ni], acc[mi][ni]);          \
    }

// QKV epilogue: z=0 Q (pre-scaled), z=1 K, z=2 V transposed [B,H,DK,S]
__global__ __launch_bounds__(256)
void gemm_qkv_b(const bf16* __restrict__ xb,
                const bf16* __restrict__ wqb, const bf16* __restrict__ wkb,
                const bf16* __restrict__ wvb,
                bf16* __restrict__ qws, bf16* __restrict__ kws,
                bf16* __restrict__ vtws) {
    const int z = blockIdx.z;
    const bf16* Wb = (z == 0) ? wqb : (z == 1) ? wkb : wvb;
    GEMM_B_MAINLOOP(xb, Wb)

    if (z < 2) {
        bf16* C = z ? kws : qws;
        const float sc = z ? 1.0f : SCALE2;
        #pragma unroll
        for (int mi = 0; mi < 4; ++mi)
            #pragma unroll
            for (int ni = 0; ni < 4; ++ni)
                #pragma unroll
                for (int r = 0; r < 4; ++r) {
                    int m = bm + wr * 64 + mi * 16 + lhi * 4 + r;
                    int n = bn + wc * 64 + ni * 16 + llo;
                    int b = m >> 11, s = m & (S_LEN - 1);
                    int h = n >> 6,  d = n & (DK - 1);
                    C[(((size_t)(b * NH + h) * S_LEN) + s) * DK + d] =
                        __float2bfloat16(acc[mi][ni][r] * sc);
                }
    } else {
        #pragma unroll
        for (int mi = 0; mi < 4; ++mi)
            #pragma unroll
            for (int ni = 0; ni < 4; ++ni) {
                int m0 = bm + wr * 64 + mi * 16 + lhi * 4;
                int n  = bn + wc * 64 + ni * 16 + llo;
                int b = m0 >> 11, s0 = m0 & (S_LEN - 1);
                int h = n >> 6,   d  = n & (DK - 1);
                s4_t pk;
                #pragma unroll
                for (int r = 0; r < 4; ++r) pk[r] = f2b(acc[mi][ni][r]);
                *(s4_t*)&vtws[(((size_t)(b * NH + h) * DK) + d) * S_LEN + s0] = pk;
            }
    }
}

// ---------------------------------------------------------------------------
// O-projection GEMM: 128x64 tile (512 blocks = 2/CU), g2l staging, fp32 C.
// ---------------------------------------------------------------------------
__global__ __launch_bounds__(256)
void gemm_o_b(const bf16* __restrict__ A, const bf16* __restrict__ Wb,
              float* __restrict__ C) {
    __shared__ bf16 As[128][32];
    __shared__ bf16 Bs[64][32];
    const int tid  = threadIdx.x;
    const int lane = tid & 63;
    const int w    = tid >> 6;
    const int wr   = w >> 1, wc = w & 1;
    const int lhi  = lane >> 4, llo = lane & 15;
    const int bm   = blockIdx.x * 128;
    const int bn   = blockIdx.y * 64;
    const int r0c  = tid >> 2;
    const int c0c  = (tid & 3) << 3;
    const int r1c  = (256 + tid) >> 2;
    f4_t acc[4][2] = {};
    for (int k0 = 0; k0 < 1024; k0 += 32) {
        __syncthreads();
        g2l16(A + (size_t)(bm + r0c) * 1024 + k0 + c0c,
              &As[0][0] + (size_t)tid * 8);
        g2l16(A + (size_t)(bm + r1c) * 1024 + k0 + c0c,
              &As[0][0] + (size_t)(256 + tid) * 8);
        g2l16(Wb + (size_t)(bn + r0c) * 1024 + k0 + c0c,
              &Bs[0][0] + (size_t)tid * 8);
        asm volatile("s_waitcnt vmcnt(0)" ::: "memory");
        __syncthreads();
        bf8_t af[4], bfr[2];
        #pragma unroll
        for (int i = 0; i < 4; ++i)
            af[i] = *(const bf8_t*)(&As[wr * 64 + i * 16 + llo][lhi * 8]);
        #pragma unroll
        for (int i = 0; i < 2; ++i)
            bfr[i] = *(const bf8_t*)(&Bs[wc * 32 + i * 16 + llo][lhi * 8]);
        #pragma unroll
        for (int mi = 0; mi < 4; ++mi)
            #pragma unroll
            for (int ni = 0; ni < 2; ++ni)
                acc[mi][ni] = mfma16(af[mi], bfr[ni], acc[mi][ni]);
    }
    #pragma unroll
    for (int mi = 0; mi < 4; ++mi)
        #pragma unroll
        for (int ni = 0; ni < 2; ++ni)
            #pragma unroll
            for (int r = 0; r < 4; ++r) {
                int m = bm + wr * 64 + mi * 16 + lhi * 4 + r;
                int n = bn + wc * 32 + ni * 16 + llo;
                C[(size_t)m * DM + n] = acc[mi][ni][r];
            }
}

// ---------------------------------------------------------------------------
// FALLBACK (small ws): inline-convert GEMMs
// ---------------------------------------------------------------------------
__global__ __launch_bounds__(256)
void gemm_qkv_f32(const float* __restrict__ x,
                  const float* __restrict__ wqp, const float* __restrict__ wkp,
                  const float* __restrict__ wvp,
                  bf16* __restrict__ qws, bf16* __restrict__ kws,
                  bf16* __restrict__ vtws) {
    constexpr int K = DM;
    constexpr int BM = 128, BK = 32, LDT = BK + 8;
    const int z = blockIdx.z;
    const float* W = (z == 0) ? wqp : (z == 1) ? wkp : wvp;
    __shared__ bf16 As[BM][LDT];
    __shared__ bf16 Bs[BM][LDT];
    const int tid  = threadIdx.x;
    const int lane = tid & 63;
    const int w    = tid >> 6;
    const int wr   = w >> 1, wc = w & 1;
    const int lhi  = lane >> 4, llo = lane & 15;
    const int bm   = blockIdx.x * BM;
    const int bn   = blockIdx.y * BM;
    f4_t acc[4][4] = {};
    for (int k0 = 0; k0 < K; k0 += BK) {
        __syncthreads();
        #pragma unroll
        for (int t = 0; t < 2; ++t) {
            int c   = t * 256 + tid;
            int row = c >> 2;
            int col = (c & 3) << 3;
            {
                const float* s0 = x + (size_t)(bm + row) * K + k0 + col;
                float4 f0 = *(const float4*)(s0);
                float4 f1 = *(const float4*)(s0 + 4);
                bf8_t a8;
                a8[0]=f2b(f0.x); a8[1]=f2b(f0.y); a8[2]=f2b(f0.z); a8[3]=f2b(f0.w);
                a8[4]=f2b(f1.x); a8[5]=f2b(f1.y); a8[6]=f2b(f1.z); a8[7]=f2b(f1.w);
                *(bf8_t*)(&As[row][col]) = a8;
            }
            {
                const float* s0 = W + (size_t)(bn + row) * K + k0 + col;
                float4 f0 = *(const float4*)(s0);
                float4 f1 = *(const float4*)(s0 + 4);
                bf8_t b8;
                b8[0]=f2b(f0.x); b8[1]=f2b(f0.y); b8[2]=f2b(f0.z); b8[3]=f2b(f0.w);
                b8[4]=f2b(f1.x); b8[5]=f2b(f1.y); b8[6]=f2b(f1.z); b8[7]=f2b(f1.w);
                *(bf8_t*)(&Bs[row][col]) = b8;
            }
        }
        __syncthreads();
        bf8_t af[4], bfr[4];
        #pragma unroll
        for (int i = 0; i < 4; ++i) {
            af[i]  = *(const bf8_t*)(&As[wr * 64 + i * 16 + llo][lhi * 8]);
            bfr[i] = *(const bf8_t*)(&Bs[wc * 64 + i * 16 + llo][lhi * 8]);
        }
        #pragma unroll
        for (int mi = 0; mi < 4; ++mi)
            #pragma unroll
            for (int ni = 0; ni < 4; ++ni)
                acc[mi][ni] = mfma16(af[mi], bfr[ni], acc[mi][ni]);
    }
    if (z < 2) {
        bf16* C = z ? kws : qws;
        const float sc = z ? 1.0f : SCALE2;
        #pragma unroll
        for (int mi = 0; mi < 4; ++mi)
            #pragma unroll
            for (int ni = 0; ni < 4; ++ni)
                #pragma unroll
                for (int r = 0; r < 4; ++r) {
                    int m = bm + wr * 64 + mi * 16 + lhi * 4 + r;
                    int n = bn + wc * 64 + ni * 16 + llo;
                    int b = m >> 11, s = m & (S_LEN - 1);
                    int h = n >> 6,  d = n & (DK - 1);
                    C[(((size_t)(b * NH + h) * S_LEN) + s) * DK + d] =
                        __float2bfloat16(acc[mi][ni][r] * sc);
                }
    } else {
        #pragma unroll
        for (int mi = 0; mi < 4; ++mi)
            #pragma unroll
            for (int ni = 0; ni < 4; ++ni) {
                int m0 = bm + wr * 64 + mi * 16 + lhi * 4;
                int n  = bn + wc * 64 + ni * 16 + llo;
                int b = m0 >> 11, s0 = m0 & (S_LEN - 1);
                int h = n >> 6,   d  = n & (DK - 1);
                s4_t pk;
                #pragma unroll
                for (int r = 0; r < 4; ++r) pk[r] = f2b(acc[mi][ni][r]);
                *(s4_t*)&vtws[(((size_t)(b * NH + h) * DK) + d) * S_LEN + s0] = pk;
            }
    }
}

__global__ __launch_bounds__(256)
void gemm_o_f32(const bf16* __restrict__ A, const float* __restrict__ W,
                float* __restrict__ C) {
    constexpr int N = DM;
    constexpr int K = DM;
    constexpr int BM = 128, BN = 64, BK = 32, LDT = BK + 8;
    __shared__ bf16 As[BM][LDT];
    __shared__ bf16 Bs[BN][LDT];
    const int tid  = threadIdx.x;
    const int lane = tid & 63;
    const int w    = tid >> 6;
    const int wr   = w >> 1, wc = w & 1;
    const int lhi  = lane >> 4, llo = lane & 15;
    const int bm   = blockIdx.x * BM;
    const int bn   = blockIdx.y * BN;
    f4_t acc[4][2] = {};
    for (int k0 = 0; k0 < K; k0 += BK) {
        __syncthreads();
        #pragma unroll
        for (int t = 0; t < 2; ++t) {
            int c   = t * 256 + tid;
            int row = c >> 2;
            int col = (c & 3) << 3;
            *(bf8_t*)(&As[row][col]) =
                *(const bf8_t*)(A + (size_t)(bm + row) * K + k0 + col);
        }
        {
            int row = tid >> 2;
            int col = (tid & 3) << 3;
            const float* s0 = W + (size_t)(bn + row) * K + k0 + col;
            float4 f0 = *(const float4*)(s0);
            float4 f1 = *(const float4*)(s0 + 4);
            bf8_t b8;
            b8[0]=f2b(f0.x); b8[1]=f2b(f0.y); b8[2]=f2b(f0.z); b8[3]=f2b(f0.w);
            b8[4]=f2b(f1.x); b8[5]=f2b(f1.y); b8[6]=f2b(f1.z); b8[7]=f2b(f1.w);
            *(bf8_t*)(&Bs[row][col]) = b8;
        }
        __syncthreads();
        bf8_t af[4], bfr[2];
        #pragma unroll
        for (int i = 0; i < 4; ++i)
            af[i] = *(const bf8_t*)(&As[wr * 64 + i * 16 + llo][lhi * 8]);
        #pragma unroll
        for (int i = 0; i < 2; ++i)
            bfr[i] = *(const bf8_t*)(&Bs[wc * 32 + i * 16 + llo][lhi * 8]);
        #pragma unroll
        for (int mi = 0; mi < 4; ++mi)
            #pragma unroll
            for (int ni = 0; ni < 2; ++ni)
                acc[mi][ni] = mfma16(af[mi], bfr[ni], acc[mi][ni]);
    }
    #pragma unroll
    for (int mi = 0; mi < 4; ++mi)
        #pragma unroll
        for (int ni = 0; ni < 2; ++ni)
            #pragma unroll
            for (int r = 0; r < 4; ++r) {
                int m = bm + wr * 64 + mi * 16 + lhi * 4 + r;
                int n = bn + wc * 32 + ni * 16 + llo;
                C[(size_t)m * N + n] = acc[mi][ni][r];
            }
}

// ---------------------------------------------------------------------------
// Causal flash attention, 256 thr = 4 waves, 32 q-rows per wave (2 halves of
// 16, A/B). K/V LDS fragment reads are SHARED between halves -> LDS-read per
// q-row halves vs r10; 2x ILP per wave. Zero-LDS P (permuted-K staging),
// defer-max (THR=8), double-buffered global_load_lds staging.
// ---------------------------------------------------------------------------
__global__ __launch_bounds__(256, 2)
void attn_fwd(const bf16* __restrict__ Q, const bf16* __restrict__ K,
              const bf16* __restrict__ Vt, bf16* __restrict__ AO) {
    __shared__ bf16 Ks[2][64][64];   // K rows permuted by g(p), XOR-swizzled
    __shared__ bf16 Vs[2][64][64];   // [d][kv], XOR-swizzled

    const int bh = blockIdx.x;
    const int qt = 15 - (int)blockIdx.y;     // longest-first
    const int q0 = qt * 128;
    const int nt = 2 * qt + 2;

    const bf16* Qh = Q  + (size_t)bh * S_LEN * DK;
    const bf16* Kh = K  + (size_t)bh * S_LEN * DK;
    const bf16* Vh = Vt + (size_t)bh * DK * S_LEN;

    const int tid  = threadIdx.x;
    const int lane = tid & 63;
    const int w    = tid >> 6;               // 0..3
    const int lhi  = lane >> 4, llo = lane & 15;
    const int qwA  = q0 + w * 32;            // half A first q row
    const int qwB  = qwA + 16;               // half B first q row
    const int sw   = llo & 7;                // read-side swizzle key

    const int r0   = tid >> 3;               // 0..31 staging row
    const int schk = (tid & 7) ^ (r0 & 7);   // pre-swizzled source chunk
    // K row permutation (zero-LDS-P layout): LDS row p holds global row g(p)
    const int gk0  = (((r0 >> 2) & 3) << 3) | (((r0 >> 4) & 1) << 2) | (r0 & 3);
    // rows 32..63: g(p+32) = g(p)+32

#define STAGE(kv, b)                                                          \
    do {                                                                      \
        g2l16(Kh + (size_t)((kv) + gk0) * DK + schk * 8,                      \
              &Ks[b][0][0] + (size_t)tid * 8);                                \
        g2l16(Kh + (size_t)((kv) + gk0 + 32) * DK + schk * 8,                 \
              &Ks[b][32][0] + (size_t)tid * 8);                               \
        g2l16(Vh + (size_t)r0 * S_LEN + (kv) + schk * 8,                      \
              &Vs[b][0][0] + (size_t)tid * 8);                                \
        g2l16(Vh + (size_t)(r0 + 32) * S_LEN + (kv) + schk * 8,               \
              &Vs[b][32][0] + (size_t)tid * 8);                               \
    } while (0)

    // Q B-frags for both halves (q = llo within each 16-row half)
    const bf16* qrowA = Qh + (size_t)(qwA + llo) * DK;
    const bf16* qrowB = Qh + (size_t)(qwB + llo) * DK;
    const bf8_t qfA0 = *(const bf8_t*)(qrowA + lhi * 8);
    const bf8_t qfA1 = *(const bf8_t*)(qrowA + 32 + lhi * 8);
    const bf8_t qfB0 = *(const bf8_t*)(qrowB + lhi * 8);
    const bf8_t qfB1 = *(const bf8_t*)(qrowB + 32 + lhi * 8);

    bf8_t ones;
    #pragma unroll
    for (int j = 0; j < 8; ++j) ones[j] = (short)0x3F80;

    STAGE(0, 0);
    asm volatile("s_waitcnt vmcnt(0)" ::: "memory");
    __syncthreads();

    f4_t oA[4] = {}, oB[4] = {};
    float lrA[4] = {0.f,0.f,0.f,0.f}, lrB[4] = {0.f,0.f,0.f,0.f};
    float mrA = NEG_BIG, mrB = NEG_BIG;

    for (int t = 0; t < nt; ++t) {
        const int kv0 = t * 64;
        const int cur = t & 1;

        if (t + 1 < nt) STAGE((t + 1) * 64, cur ^ 1);

        if (kv0 <= qwB + 15) {       // wave-uniform: B half still active
            const bool doA = (kv0 <= qwA + 15);

            f4_t sA[4] = {}, sB[4] = {};
            __builtin_amdgcn_s_setprio(1);
            #pragma unroll
            for (int nf = 0; nf < 4; ++nf) {
                const int R = nf * 16 + llo;
                bf8_t k0f = *(const bf8_t*)&Ks[cur][R][(lhi ^ sw) * 8];
                bf8_t k1f = *(const bf8_t*)&Ks[cur][R][((4 + lhi) ^ sw) * 8];
                sB[nf] = mfma16(k0f, qfB0, sB[nf]);
                sB[nf] = mfma16(k1f, qfB1, sB[nf]);
                if (doA) {
                    sA[nf] = mfma16(k0f, qfA0, sA[nf]);
                    sA[nf] = mfma16(k1f, qfA1, sA[nf]);
                }
            }
            __builtin_amdgcn_s_setprio(0);

            // causal masks (kv index = kv0 + lhi*8 + 4*(nf&1) + r + 32*(nf>>1))
            if (kv0 + 63 > qwB) {
                #pragma unroll
                for (int nf = 0; nf < 4; ++nf)
                    #pragma unroll
                    for (int r = 0; r < 4; ++r)
                        if (kv0 + lhi * 8 + ((nf & 1) << 2) + r + ((nf >> 1) << 5)
                            > qwB + llo)
                            sB[nf][r] = NEG_BIG;
            }
            if (doA && kv0 + 63 > qwA) {
                #pragma unroll
                for (int nf = 0; nf < 4; ++nf)
                    #pragma unroll
                    for (int r = 0; r < 4; ++r)
                        if (kv0 + lhi * 8 + ((nf & 1) << 2) + r + ((nf >> 1) << 5)
                            > qwA + llo)
                            sA[nf][r] = NEG_BIG;
            }

            float pmA = NEG_BIG, pmB = sB[0][0];
            #pragma unroll
            for (int nf = 0; nf < 4; ++nf)
                #pragma unroll
                for (int r = 0; r < 4; ++r) pmB = fmaxf(pmB, sB[nf][r]);
            if (doA) {
                pmA = sA[0][0];
                #pragma unroll
                for (int nf = 0; nf < 4; ++nf)
                    #pragma unroll
                    for (int r = 0; r < 4; ++r) pmA = fmaxf(pmA, sA[nf][r]);
            }
            pmB = fmaxf(pmB, __shfl_xor(pmB, 16));
            pmB = fmaxf(pmB, __shfl_xor(pmB, 32));
            pmA = fmaxf(pmA, __shfl_xor(pmA, 16));
            pmA = fmaxf(pmA, __shfl_xor(pmA, 32));

            // defer-max (T13): rescale only when a row grew past THR=8
            if (__any(fmaxf(pmA - mrA, pmB - mrB) > 8.0f)) {
                float mnA = fmaxf(mrA, pmA), mnB = fmaxf(mrB, pmB);
                float aA = exp2f(mrA - mnA), aB = exp2f(mrB - mnB);
                mrA = mnA; mrB = mnB;
                float aoA[4], aoB[4];
                #pragma unroll
                for (int r = 0; r < 4; ++r) {
                    aoA[r] = __shfl(aA, lhi * 4 + r);
                    aoB[r] = __shfl(aB, lhi * 4 + r);
                }
                #pragma unroll
                for (int df = 0; df < 4; ++df)
                    #pragma unroll
                    for (int r = 0; r < 4; ++r) {
                        oA[df][r] *= aoA[r];
                        oB[df][r] *= aoB[r];
                    }
                #pragma unroll
                for (int r = 0; r < 4; ++r) { lrA[r] *= aoA[r]; lrB[r] *= aoB[r]; }
            }

            // P = exp2(s - mr), packed IN-LANE into PV A-frags (no LDS)
            bf8_t paA0 = ones, paA1 = ones, paB0, paB1;
            #pragma unroll
            for (int r = 0; r < 4; ++r) {
                paB0[r]     = f2b(exp2f(sB[0][r] - mrB));
                paB0[4 + r] = f2b(exp2f(sB[1][r] - mrB));
                paB1[r]     = f2b(exp2f(sB[2][r] - mrB));
                paB1[4 + r] = f2b(exp2f(sB[3][r] - mrB));
            }
            if (doA) {
                #pragma unroll
                for (int r = 0; r < 4; ++r) {
                    paA0[r]     = f2b(exp2f(sA[0][r] - mrA));
                    paA0[4 + r] = f2b(exp2f(sA[1][r] - mrA));
                    paA1[r]     = f2b(exp2f(sA[2][r] - mrA));
                    paA1[4 + r] = f2b(exp2f(sA[3][r] - mrA));
                }
            }

            f4_t rsB = {};
            rsB = mfma16(paB0, ones, rsB);
            rsB = mfma16(paB1, ones, rsB);
            f4_t rsA = {};
            if (doA) {
                rsA = mfma16(paA0, ones, rsA);
                rsA = mfma16(paA1, ones, rsA);
            }

            __builtin_amdgcn_s_setprio(1);
            #pragma unroll
            for (int df = 0; df < 4; ++df) {
                const int R = df * 16 + llo;
                bf8_t vb0 = *(const bf8_t*)&Vs[cur][R][(lhi ^ sw) * 8];
                bf8_t vb1 = *(const bf8_t*)&Vs[cur][R][((4 + lhi) ^ sw) * 8];
                oB[df] = mfma16(paB0, vb0, oB[df]);
                oB[df] = mfma16(paB1, vb1, oB[df]);
                if (doA) {
                    oA[df] = mfma16(paA0, vb0, oA[df]);
                    oA[df] = mfma16(paA1, vb1, oA[df]);
                }
            }
            __builtin_amdgcn_s_setprio(0);

            #pragma unroll
            for (int r = 0; r < 4; ++r) {
                lrB[r] += rsB[r];
                if (doA) lrA[r] += rsA[r];
            }
        }

        asm volatile("s_waitcnt vmcnt(0)" ::: "memory");
        __syncthreads();
    }
#undef STAGE

    const int b = bh >> 4, h = bh & (NH - 1);
    #pragma unroll
    for (int r = 0; r < 4; ++r) {
        float invA = 1.0f / lrA[r];
        float invB = 1.0f / lrB[r];
        int qA = qwA + lhi * 4 + r;
        int qB = qwB + lhi * 4 + r;
        bf16* orowA = AO + ((size_t)(b * S_LEN + qA) * DM) + h * DK;
        bf16* orowB = AO + ((size_t)(b * S_LEN + qB) * DM) + h * DK;
        #pragma unroll
        for (int df = 0; df < 4; ++df) {
            orowA[df * 16 + llo] = __float2bfloat16(oA[df][r] * invA);
            orowB[df * 16 + llo] = __float2bfloat16(oB[df][r] * invB);
        }
    }
}

// ---------------------------------------------------------------------------
extern "C" void kernel_launch(void* const* d_in, const int* in_sizes, int n_in,
                              void* d_out, int out_size, void* d_ws, size_t ws_size,
                              hipStream_t stream) {
    const float* x  = (const float*)d_in[0];
    const float* wq = (const float*)d_in[1];
    const float* wk = (const float*)d_in[2];
    const float* wv = (const float*)d_in[3];
    const float* wo = (const float*)d_in[4];
    float* out = (float*)d_out;

    const size_t SEG   = 1u << 20;
    const size_t elems = 4 * SEG;
    const size_t need_fast = (8 * SEG + 3 * elems) * sizeof(bf16);  // 40 MB

    dim3 blk(256);

    if (ws_size >= need_fast) {
        bf16* ob   = (bf16*)d_ws;
        bf16* xb   = ob;
        bf16* wqb  = ob + 4 * SEG;
        bf16* wkb  = ob + 5 * SEG;
        bf16* wvb  = ob + 6 * SEG;
        bf16* wob  = ob + 7 * SEG;
        bf16* qws  = ob + 8 * SEG;
        bf16* kws  = qws + elems;
        bf16* vtws = kws + elems;
        bf16* aws  = xb;                        // alias: xb dead after QKV GEMMs

        cvt_all<<<4096, blk, 0, stream>>>(x, wq, wk, wv, wo, ob);
        gemm_qkv_b<<<dim3(32, 8, 3), blk, 0, stream>>>(xb, wqb, wkb, wvb,
                                                       qws, kws, vtws);
        attn_fwd<<<dim3(NBATCH * NH, 16), blk, 0, stream>>>(qws, kws, vtws, aws);
        gemm_o_b<<<dim3(32, 16), blk, 0, stream>>>(aws, wob, out);
    } else {
        if (ws_size < elems * 4 * sizeof(bf16)) return;
        bf16* qws  = (bf16*)d_ws;
        bf16* kws  = qws + elems;
        bf16* vtws = kws + elems;
        bf16* aws  = vtws + elems;

        gemm_qkv_f32<<<dim3(32, 8, 3), blk, 0, stream>>>(x, wq, wk, wv,
                                                         qws, kws, vtws);
        attn_fwd<<<dim3(NBATCH * NH, 16), blk, 0, stream>>>(qws, kws, vtws, aws);
        gemm_o_f32<<<dim3(32, 16), blk, 0, stream>>>(aws, wo, out);
    }
}

// Round 12
// 103.570 us; speedup vs baseline: 1.2635x; 1.2635x over previous
//
#include <hip/hip_runtime.h>
#include <hip/hip_bf16.h>
#include <stdint.h>

#define S_LEN 2048
#define DM    1024
#define NH    16
#define DK    64
#define NBATCH 2

typedef __attribute__((ext_vector_type(8))) short bf8_t;   // 8 bf16 (4 VGPRs)
typedef __attribute__((ext_vector_type(4))) short s4_t;    // 4 bf16 (8B)
typedef __attribute__((ext_vector_type(4))) float f4_t;    // MFMA accum

using bf16 = __hip_bfloat16;

#define NEG_BIG (-1.0e30f)
#define SCALE2  (0.125f * 1.44269504088896f)   // 1/sqrt(dk) * log2(e)

static __device__ __forceinline__ f4_t mfma16(bf8_t a, bf8_t b, f4_t c) {
    return __builtin_amdgcn_mfma_f32_16x16x32_bf16(a, b, c, 0, 0, 0);
}

static __device__ __forceinline__ short f2b(float f) {
    __hip_bfloat16 h = __float2bfloat16(f);
    return *reinterpret_cast<short*>(&h);
}

// async global->LDS, 16B per lane. Dest must be linear: uniform base + lane*16.
static __device__ __forceinline__ void g2l16(const bf16* g, bf16* l) {
#if __has_builtin(__builtin_amdgcn_global_load_lds)
    __builtin_amdgcn_global_load_lds(
        (const __attribute__((address_space(1))) void*)g,
        (__attribute__((address_space(3))) void*)l, 16, 0, 0);
#else
    *(bf8_t*)l = *(const bf8_t*)g;   // correct, slower
#endif
}

// ---------------------------------------------------------------------------
// fp32 -> bf16 pre-convert: ob = [xb 4M | wqb 1M | wkb 1M | wvb 1M | wob 1M]
// ---------------------------------------------------------------------------
__global__ __launch_bounds__(256)
void cvt_all(const float* __restrict__ x,  const float* __restrict__ wq,
             const float* __restrict__ wk, const float* __restrict__ wv,
             const float* __restrict__ wo, bf16* __restrict__ ob) {
    const size_t SEG = 1u << 20;
    size_t i = ((size_t)blockIdx.x * 256 + threadIdx.x) * 8;
    const float* src;
    if      (i < 4 * SEG) src = x  + i;
    else if (i < 5 * SEG) src = wq + (i - 4 * SEG);
    else if (i < 6 * SEG) src = wk + (i - 5 * SEG);
    else if (i < 7 * SEG) src = wv + (i - 6 * SEG);
    else                  src = wo + (i - 7 * SEG);
    float4 f0 = *(const float4*)(src);
    float4 f1 = *(const float4*)(src + 4);
    bf8_t v;
    v[0]=f2b(f0.x); v[1]=f2b(f0.y); v[2]=f2b(f0.z); v[3]=f2b(f0.w);
    v[4]=f2b(f1.x); v[5]=f2b(f1.y); v[6]=f2b(f1.z); v[7]=f2b(f1.w);
    *(bf8_t*)(ob + i) = v;
}

// ---------------------------------------------------------------------------
// bf16 GEMM main loop (m97 structure): 128x128 tile, BK=32, LINEAR LDS,
// global_load_lds width-16 staging, 4 waves 2x2, 4x4 16x16 frags.
// ---------------------------------------------------------------------------
#define GEMM_B_MAINLOOP(Aptr, Bptr)                                          \
    __shared__ bf16 As[128][32];                                             \
    __shared__ bf16 Bs[128][32];                                             \
    const int tid  = threadIdx.x;                                            \
    const int lane = tid & 63;                                               \
    const int w    = tid >> 6;                                               \
    const int wr   = w >> 1, wc = w & 1;                                     \
    const int lhi  = lane >> 4, llo = lane & 15;                             \
    const int bm   = blockIdx.x * 128;                                       \
    const int bn   = blockIdx.y * 128;                                       \
    const int r0c  = tid >> 2;                 /* chunk row, t=0 */          \
    const int c0c  = (tid & 3) << 3;           /* chunk col      */          \
    const int r1c  = (256 + tid) >> 2;                                       \
    f4_t acc[4][4] = {};                                                     \
    for (int k0 = 0; k0 < 1024; k0 += 32) {                                  \
        __syncthreads();                                                     \
        g2l16(Aptr + (size_t)(bm + r0c) * 1024 + k0 + c0c,                   \
              &As[0][0] + (size_t)tid * 8);                                  \
        g2l16(Aptr + (size_t)(bm + r1c) * 1024 + k0 + c0c,                   \
              &As[0][0] + (size_t)(256 + tid) * 8);                          \
        g2l16(Bptr + (size_t)(bn + r0c) * 1024 + k0 + c0c,                   \
              &Bs[0][0] + (size_t)tid * 8);                                  \
        g2l16(Bptr + (size_t)(bn + r1c) * 1024 + k0 + c0c,                   \
              &Bs[0][0] + (size_t)(256 + tid) * 8);                          \
        asm volatile("s_waitcnt vmcnt(0)" ::: "memory");                     \
        __syncthreads();                                                     \
        bf8_t af[4], bfr[4];                                                 \
        _Pragma("unroll")                                                    \
        for (int i = 0; i < 4; ++i) {                                        \
            af[i]  = *(const bf8_t*)(&As[wr * 64 + i * 16 + llo][lhi * 8]);  \
            bfr[i] = *(const bf8_t*)(&Bs[wc * 64 + i * 16 + llo][lhi * 8]);  \
        }                                                                    \
        _Pragma("unroll")                                                    \
        for (int mi = 0; mi < 4; ++mi)                                       \
            _Pragma("unroll")                                                \
            for (int ni = 0; ni < 4; ++ni)                                   \
                acc[mi][ni] = mfma16(af[mi], bfr[ni], acc[mi][ni]);          \
    }

// QKV epilogue: z=0 Q (pre-scaled), z=1 K, z=2 V transposed [B,H,DK,S]
__global__ __launch_bounds__(256)
void gemm_qkv_b(const bf16* __restrict__ xb,
                const bf16* __restrict__ wqb, const bf16* __restrict__ wkb,
                const bf16* __restrict__ wvb,
                bf16* __restrict__ qws, bf16* __restrict__ kws,
                bf16* __restrict__ vtws) {
    const int z = blockIdx.z;
    const bf16* Wb = (z == 0) ? wqb : (z == 1) ? wkb : wvb;
    GEMM_B_MAINLOOP(xb, Wb)

    if (z < 2) {
        bf16* C = z ? kws : qws;
        const float sc = z ? 1.0f : SCALE2;
        #pragma unroll
        for (int mi = 0; mi < 4; ++mi)
            #pragma unroll
            for (int ni = 0; ni < 4; ++ni)
                #pragma unroll
                for (int r = 0; r < 4; ++r) {
                    int m = bm + wr * 64 + mi * 16 + lhi * 4 + r;
                    int n = bn + wc * 64 + ni * 16 + llo;
                    int b = m >> 11, s = m & (S_LEN - 1);
                    int h = n >> 6,  d = n & (DK - 1);
                    C[(((size_t)(b * NH + h) * S_LEN) + s) * DK + d] =
                        __float2bfloat16(acc[mi][ni][r] * sc);
                }
    } else {
        #pragma unroll
        for (int mi = 0; mi < 4; ++mi)
            #pragma unroll
            for (int ni = 0; ni < 4; ++ni) {
                int m0 = bm + wr * 64 + mi * 16 + lhi * 4;
                int n  = bn + wc * 64 + ni * 16 + llo;
                int b = m0 >> 11, s0 = m0 & (S_LEN - 1);
                int h = n >> 6,   d  = n & (DK - 1);
                s4_t pk;
                #pragma unroll
                for (int r = 0; r < 4; ++r) pk[r] = f2b(acc[mi][ni][r]);
                *(s4_t*)&vtws[(((size_t)(b * NH + h) * DK) + d) * S_LEN + s0] = pk;
            }
    }
}

// ---------------------------------------------------------------------------
// O-projection GEMM: 128x64 tile (512 blocks = 2/CU), g2l staging, fp32 C.
// ---------------------------------------------------------------------------
__global__ __launch_bounds__(256)
void gemm_o_b(const bf16* __restrict__ A, const bf16* __restrict__ Wb,
              float* __restrict__ C) {
    __shared__ bf16 As[128][32];
    __shared__ bf16 Bs[64][32];
    const int tid  = threadIdx.x;
    const int lane = tid & 63;
    const int w    = tid >> 6;
    const int wr   = w >> 1, wc = w & 1;
    const int lhi  = lane >> 4, llo = lane & 15;
    const int bm   = blockIdx.x * 128;
    const int bn   = blockIdx.y * 64;
    const int r0c  = tid >> 2;
    const int c0c  = (tid & 3) << 3;
    const int r1c  = (256 + tid) >> 2;
    f4_t acc[4][2] = {};
    for (int k0 = 0; k0 < 1024; k0 += 32) {
        __syncthreads();
        g2l16(A + (size_t)(bm + r0c) * 1024 + k0 + c0c,
              &As[0][0] + (size_t)tid * 8);
        g2l16(A + (size_t)(bm + r1c) * 1024 + k0 + c0c,
              &As[0][0] + (size_t)(256 + tid) * 8);
        g2l16(Wb + (size_t)(bn + r0c) * 1024 + k0 + c0c,
              &Bs[0][0] + (size_t)tid * 8);
        asm volatile("s_waitcnt vmcnt(0)" ::: "memory");
        __syncthreads();
        bf8_t af[4], bfr[2];
        #pragma unroll
        for (int i = 0; i < 4; ++i)
            af[i] = *(const bf8_t*)(&As[wr * 64 + i * 16 + llo][lhi * 8]);
        #pragma unroll
        for (int i = 0; i < 2; ++i)
            bfr[i] = *(const bf8_t*)(&Bs[wc * 32 + i * 16 + llo][lhi * 8]);
        #pragma unroll
        for (int mi = 0; mi < 4; ++mi)
            #pragma unroll
            for (int ni = 0; ni < 2; ++ni)
                acc[mi][ni] = mfma16(af[mi], bfr[ni], acc[mi][ni]);
    }
    #pragma unroll
    for (int mi = 0; mi < 4; ++mi)
        #pragma unroll
        for (int ni = 0; ni < 2; ++ni)
            #pragma unroll
            for (int r = 0; r < 4; ++r) {
                int m = bm + wr * 64 + mi * 16 + lhi * 4 + r;
                int n = bn + wc * 32 + ni * 16 + llo;
                C[(size_t)m * DM + n] = acc[mi][ni][r];
            }
}

// ---------------------------------------------------------------------------
// FALLBACK (small ws): inline-convert GEMMs
// ---------------------------------------------------------------------------
__global__ __launch_bounds__(256)
void gemm_qkv_f32(const float* __restrict__ x,
                  const float* __restrict__ wqp, const float* __restrict__ wkp,
                  const float* __restrict__ wvp,
                  bf16* __restrict__ qws, bf16* __restrict__ kws,
                  bf16* __restrict__ vtws) {
    constexpr int K = DM;
    constexpr int BM = 128, BK = 32, LDT = BK + 8;
    const int z = blockIdx.z;
    const float* W = (z == 0) ? wqp : (z == 1) ? wkp : wvp;
    __shared__ bf16 As[BM][LDT];
    __shared__ bf16 Bs[BM][LDT];
    const int tid  = threadIdx.x;
    const int lane = tid & 63;
    const int w    = tid >> 6;
    const int wr   = w >> 1, wc = w & 1;
    const int lhi  = lane >> 4, llo = lane & 15;
    const int bm   = blockIdx.x * BM;
    const int bn   = blockIdx.y * BM;
    f4_t acc[4][4] = {};
    for (int k0 = 0; k0 < K; k0 += BK) {
        __syncthreads();
        #pragma unroll
        for (int t = 0; t < 2; ++t) {
            int c   = t * 256 + tid;
            int row = c >> 2;
            int col = (c & 3) << 3;
            {
                const float* s0 = x + (size_t)(bm + row) * K + k0 + col;
                float4 f0 = *(const float4*)(s0);
                float4 f1 = *(const float4*)(s0 + 4);
                bf8_t a8;
                a8[0]=f2b(f0.x); a8[1]=f2b(f0.y); a8[2]=f2b(f0.z); a8[3]=f2b(f0.w);
                a8[4]=f2b(f1.x); a8[5]=f2b(f1.y); a8[6]=f2b(f1.z); a8[7]=f2b(f1.w);
                *(bf8_t*)(&As[row][col]) = a8;
            }
            {
                const float* s0 = W + (size_t)(bn + row) * K + k0 + col;
                float4 f0 = *(const float4*)(s0);
                float4 f1 = *(const float4*)(s0 + 4);
                bf8_t b8;
                b8[0]=f2b(f0.x); b8[1]=f2b(f0.y); b8[2]=f2b(f0.z); b8[3]=f2b(f0.w);
                b8[4]=f2b(f1.x); b8[5]=f2b(f1.y); b8[6]=f2b(f1.z); b8[7]=f2b(f1.w);
                *(bf8_t*)(&Bs[row][col]) = b8;
            }
        }
        __syncthreads();
        bf8_t af[4], bfr[4];
        #pragma unroll
        for (int i = 0; i < 4; ++i) {
            af[i]  = *(const bf8_t*)(&As[wr * 64 + i * 16 + llo][lhi * 8]);
            bfr[i] = *(const bf8_t*)(&Bs[wc * 64 + i * 16 + llo][lhi * 8]);
        }
        #pragma unroll
        for (int mi = 0; mi < 4; ++mi)
            #pragma unroll
            for (int ni = 0; ni < 4; ++ni)
                acc[mi][ni] = mfma16(af[mi], bfr[ni], acc[mi][ni]);
    }
    if (z < 2) {
        bf16* C = z ? kws : qws;
        const float sc = z ? 1.0f : SCALE2;
        #pragma unroll
        for (int mi = 0; mi < 4; ++mi)
            #pragma unroll
            for (int ni = 0; ni < 4; ++ni)
                #pragma unroll
                for (int r = 0; r < 4; ++r) {
                    int m = bm + wr * 64 + mi * 16 + lhi * 4 + r;
                    int n = bn + wc * 64 + ni * 16 + llo;
                    int b = m >> 11, s = m & (S_LEN - 1);
                    int h = n >> 6,  d = n & (DK - 1);
                    C[(((size_t)(b * NH + h) * S_LEN) + s) * DK + d] =
                        __float2bfloat16(acc[mi][ni][r] * sc);
                }
    } else {
        #pragma unroll
        for (int mi = 0; mi < 4; ++mi)
            #pragma unroll
            for (int ni = 0; ni < 4; ++ni) {
                int m0 = bm + wr * 64 + mi * 16 + lhi * 4;
                int n  = bn + wc * 64 + ni * 16 + llo;
                int b = m0 >> 11, s0 = m0 & (S_LEN - 1);
                int h = n >> 6,   d  = n & (DK - 1);
                s4_t pk;
                #pragma unroll
                for (int r = 0; r < 4; ++r) pk[r] = f2b(acc[mi][ni][r]);
                *(s4_t*)&vtws[(((size_t)(b * NH + h) * DK) + d) * S_LEN + s0] = pk;
            }
    }
}

__global__ __launch_bounds__(256)
void gemm_o_f32(const bf16* __restrict__ A, const float* __restrict__ W,
                float* __restrict__ C) {
    constexpr int N = DM;
    constexpr int K = DM;
    constexpr int BM = 128, BN = 64, BK = 32, LDT = BK + 8;
    __shared__ bf16 As[BM][LDT];
    __shared__ bf16 Bs[BN][LDT];
    const int tid  = threadIdx.x;
    const int lane = tid & 63;
    const int w    = tid >> 6;
    const int wr   = w >> 1, wc = w & 1;
    const int lhi  = lane >> 4, llo = lane & 15;
    const int bm   = blockIdx.x * BM;
    const int bn   = blockIdx.y * BN;
    f4_t acc[4][2] = {};
    for (int k0 = 0; k0 < K; k0 += BK) {
        __syncthreads();
        #pragma unroll
        for (int t = 0; t < 2; ++t) {
            int c   = t * 256 + tid;
            int row = c >> 2;
            int col = (c & 3) << 3;
            *(bf8_t*)(&As[row][col]) =
                *(const bf8_t*)(A + (size_t)(bm + row) * K + k0 + col);
        }
        {
            int row = tid >> 2;
            int col = (tid & 3) << 3;
            const float* s0 = W + (size_t)(bn + row) * K + k0 + col;
            float4 f0 = *(const float4*)(s0);
            float4 f1 = *(const float4*)(s0 + 4);
            bf8_t b8;
            b8[0]=f2b(f0.x); b8[1]=f2b(f0.y); b8[2]=f2b(f0.z); b8[3]=f2b(f0.w);
            b8[4]=f2b(f1.x); b8[5]=f2b(f1.y); b8[6]=f2b(f1.z); b8[7]=f2b(f1.w);
            *(bf8_t*)(&Bs[row][col]) = b8;
        }
        __syncthreads();
        bf8_t af[4], bfr[2];
        #pragma unroll
        for (int i = 0; i < 4; ++i)
            af[i] = *(const bf8_t*)(&As[wr * 64 + i * 16 + llo][lhi * 8]);
        #pragma unroll
        for (int i = 0; i < 2; ++i)
            bfr[i] = *(const bf8_t*)(&Bs[wc * 32 + i * 16 + llo][lhi * 8]);
        #pragma unroll
        for (int mi = 0; mi < 4; ++mi)
            #pragma unroll
            for (int ni = 0; ni < 2; ++ni)
                acc[mi][ni] = mfma16(af[mi], bfr[ni], acc[mi][ni]);
    }
    #pragma unroll
    for (int mi = 0; mi < 4; ++mi)
        #pragma unroll
        for (int ni = 0; ni < 2; ++ni)
            #pragma unroll
            for (int r = 0; r < 4; ++r) {
                int m = bm + wr * 64 + mi * 16 + lhi * 4 + r;
                int n = bn + wc * 32 + ni * 16 + llo;
                C[(size_t)m * N + n] = acc[mi][ni][r];
            }
}

// ---------------------------------------------------------------------------
// Causal flash attention, SPLIT-KV: 512 thr = 8 waves = 4 q-subtiles (16 rows)
// x 2 KV-groups. Group g processes interleaved KV tiles t = 2s+g -> the
// per-block serial chain is ceil(nt/2) steps (was nt). Partial online-softmax
// states merged at the end via LDS (lane-local). Zero-LDS P (permuted-K
// staging), XOR swizzle, defer-max, double-buffered global_load_lds per group.
// Q-tile 64 rows; grid (32 bh, 32 qt) longest-first; LDS 64KB -> 2 blocks/CU.
// ---------------------------------------------------------------------------
__global__ __launch_bounds__(512, 4)
void attn_fwd(const bf16* __restrict__ Q, const bf16* __restrict__ K,
              const bf16* __restrict__ Vt, bf16* __restrict__ AO) {
    __shared__ bf16 Ks[2][2][64][64];   // [group][buf], K rows permuted, swizzled
    __shared__ bf16 Vs[2][2][64][64];   // [group][buf], [d][kv], swizzled

    const int bh = blockIdx.x;
    const int qt = 31 - (int)blockIdx.y;     // longest-first (64-row q-tiles)
    const int q0 = qt * 64;
    const int nt = qt + 1;                   // KV tiles for this q-tile
    const int S  = (nt + 1) >> 1;            // steps (max over groups)

    const bf16* Qh = Q  + (size_t)bh * S_LEN * DK;
    const bf16* Kh = K  + (size_t)bh * S_LEN * DK;
    const bf16* Vh = Vt + (size_t)bh * DK * S_LEN;

    const int tid  = threadIdx.x;
    const int lane = tid & 63;
    const int w    = tid >> 6;               // 0..7
    const int g    = w >> 2;                 // KV group 0/1
    const int qsub = w & 3;                  // q-subtile within 64 rows
    const int lhi  = lane >> 4, llo = lane & 15;
    const int qw   = q0 + qsub * 16;         // wave's first q row
    const int sw   = llo & 7;                // read-side swizzle key

    const int srow = tid >> 3;               // 0..63 staging row
    const int schk = (tid & 7) ^ (srow & 7); // pre-swizzled source chunk
    // K row permutation (zero-LDS-P): LDS row p holds global row g(p)
    const int gk = (((srow >> 2) & 3) << 3) | (((srow >> 4) & 1) << 2)
                 | (srow & 3) | ((srow >> 5) << 5);

    // stage tile t (kv0 = t*64) into group gg buffer b — all 512 threads
#define STAGE(t, gg, b)                                                       \
    do {                                                                      \
        const int kv_ = (t) * 64;                                             \
        g2l16(Kh + (size_t)(kv_ + gk) * DK + schk * 8,                        \
              &Ks[gg][b][0][0] + (size_t)tid * 8);                            \
        g2l16(Vh + (size_t)srow * S_LEN + kv_ + schk * 8,                     \
              &Vs[gg][b][0][0] + (size_t)tid * 8);                            \
    } while (0)

    // Q B-frags (q = llo within wave tile); waves w and w+4 load same rows
    const bf16* qrow = Qh + (size_t)(qw + llo) * DK;
    const bf8_t qf0 = *(const bf8_t*)(qrow + lhi * 8);
    const bf8_t qf1 = *(const bf8_t*)(qrow + 32 + lhi * 8);

    bf8_t ones;
    #pragma unroll
    for (int j = 0; j < 8; ++j) ones[j] = (short)0x3F80;

    // prologue: stage first tile of each group
    STAGE(0, 0, 0);
    if (1 < nt) STAGE(1, 1, 0);
    asm volatile("s_waitcnt vmcnt(0)" ::: "memory");
    __syncthreads();

    f4_t o[4] = {};
    float lr[4] = {0.f, 0.f, 0.f, 0.f};      // o-layout (q = lhi*4+r)
    float mr = NEG_BIG;                       // per-lane, q = llo

    for (int s = 0; s < S; ++s) {
        const int tg  = 2 * s + g;           // this wave's tile index
        const int cur = s & 1;
        const int tn0 = 2 * (s + 1);         // next tiles to stage
        if (tn0 < nt)     STAGE(tn0,     0, cur ^ 1);
        if (tn0 + 1 < nt) STAGE(tn0 + 1, 1, cur ^ 1);

        const int kv0 = tg * 64;
        if (tg < nt && kv0 <= qw + 15) {     // wave-uniform activity test
            f4_t sc[4] = {};
            __builtin_amdgcn_s_setprio(1);
            #pragma unroll
            for (int nf = 0; nf < 4; ++nf) {
                const int R = nf * 16 + llo;
                bf8_t k0f = *(const bf8_t*)&Ks[g][cur][R][(lhi ^ sw) * 8];
                bf8_t k1f = *(const bf8_t*)&Ks[g][cur][R][((4 + lhi) ^ sw) * 8];
                sc[nf] = mfma16(k0f, qf0, sc[nf]);
                sc[nf] = mfma16(k1f, qf1, sc[nf]);
            }
            __builtin_amdgcn_s_setprio(0);

            if (kv0 + 63 > qw) {   // tile crosses this wave's diagonal
                #pragma unroll
                for (int nf = 0; nf < 4; ++nf)
                    #pragma unroll
                    for (int r = 0; r < 4; ++r)
                        if (kv0 + lhi * 8 + ((nf & 1) << 2) + r + ((nf >> 1) << 5)
                            > qw + llo)
                            sc[nf][r] = NEG_BIG;
            }

            float pm = sc[0][0];
            #pragma unroll
            for (int nf = 0; nf < 4; ++nf)
                #pragma unroll
                for (int r = 0; r < 4; ++r) pm = fmaxf(pm, sc[nf][r]);
            pm = fmaxf(pm, __shfl_xor(pm, 16));
            pm = fmaxf(pm, __shfl_xor(pm, 32));

            // defer-max (T13): rescale only when a row grew past THR=8
            if (__any(pm > mr + 8.0f)) {
                float mn = fmaxf(mr, pm);
                float alpha = exp2f(mr - mn);
                mr = mn;
                float ao[4];
                #pragma unroll
                for (int r = 0; r < 4; ++r) ao[r] = __shfl(alpha, lhi * 4 + r);
                #pragma unroll
                for (int df = 0; df < 4; ++df)
                    #pragma unroll
                    for (int r = 0; r < 4; ++r) o[df][r] *= ao[r];
                #pragma unroll
                for (int r = 0; r < 4; ++r) lr[r] *= ao[r];
            }

            // P = exp2(s - mr), packed IN-LANE into PV A-frags (no LDS)
            bf8_t pa0, pa1;
            #pragma unroll
            for (int r = 0; r < 4; ++r) {
                pa0[r]     = f2b(exp2f(sc[0][r] - mr));
                pa0[4 + r] = f2b(exp2f(sc[1][r] - mr));
                pa1[r]     = f2b(exp2f(sc[2][r] - mr));
                pa1[4 + r] = f2b(exp2f(sc[3][r] - mr));
            }

            f4_t rsacc = {};
            rsacc = mfma16(pa0, ones, rsacc);
            rsacc = mfma16(pa1, ones, rsacc);

            __builtin_amdgcn_s_setprio(1);
            #pragma unroll
            for (int df = 0; df < 4; ++df) {
                const int R = df * 16 + llo;
                bf8_t vb0 = *(const bf8_t*)&Vs[g][cur][R][(lhi ^ sw) * 8];
                bf8_t vb1 = *(const bf8_t*)&Vs[g][cur][R][((4 + lhi) ^ sw) * 8];
                o[df] = mfma16(pa0, vb0, o[df]);
                o[df] = mfma16(pa1, vb1, o[df]);
            }
            __builtin_amdgcn_s_setprio(0);

            #pragma unroll
            for (int r = 0; r < 4; ++r) lr[r] += rsacc[r];
        }

        asm volatile("s_waitcnt vmcnt(0)" ::: "memory");
        __syncthreads();
    }
#undef STAGE

    // ---- merge the two KV-groups' partial states (lane-local via LDS) ----
    // m to o-layout for both groups
    float mo[4];
    #pragma unroll
    for (int r = 0; r < 4; ++r) mo[r] = __shfl(mr, lhi * 4 + r);

    float* xch = (float*)&Ks[0][0][0][0];    // 24KB of the 32KB K region
    if (g == 1) {
        float* p = xch + ((size_t)(qsub * 64 + lane)) * 24;
        #pragma unroll
        for (int df = 0; df < 4; ++df)
            #pragma unroll
            for (int r = 0; r < 4; ++r) p[df * 4 + r] = o[df][r];
        #pragma unroll
        for (int r = 0; r < 4; ++r) { p[16 + r] = lr[r]; p[20 + r] = mo[r]; }
    }
    __syncthreads();
    if (g == 0) {
        const float* p = xch + ((size_t)(qsub * 64 + lane)) * 24;
        const int b = bh >> 4, h = bh & (NH - 1);
        #pragma unroll
        for (int r = 0; r < 4; ++r) {
            float m1 = p[20 + r];
            float M  = fmaxf(mo[r], m1);
            float a0 = exp2f(mo[r] - M);
            float a1 = exp2f(m1 - M);
            float l  = lr[r] * a0 + p[16 + r] * a1;
            float inv = 1.0f / l;
            int q = qw + lhi * 4 + r;
            bf16* orow = AO + ((size_t)(b * S_LEN + q) * DM) + h * DK;
            #pragma unroll
            for (int df = 0; df < 4; ++df) {
                float v = o[df][r] * a0 + p[df * 4 + r] * a1;
                orow[df * 16 + llo] = __float2bfloat16(v * inv);
            }
        }
    }
}

// ---------------------------------------------------------------------------
extern "C" void kernel_launch(void* const* d_in, const int* in_sizes, int n_in,
                              void* d_out, int out_size, void* d_ws, size_t ws_size,
                              hipStream_t stream) {
    const float* x  = (const float*)d_in[0];
    const float* wq = (const float*)d_in[1];
    const float* wk = (const float*)d_in[2];
    const float* wv = (const float*)d_in[3];
    const float* wo = (const float*)d_in[4];
    float* out = (float*)d_out;

    const size_t SEG   = 1u << 20;
    const size_t elems = 4 * SEG;
    const size_t need_fast = (8 * SEG + 3 * elems) * sizeof(bf16);  // 40 MB

    dim3 blk(256);

    if (ws_size >= need_fast) {
        bf16* ob   = (bf16*)d_ws;
        bf16* xb   = ob;
        bf16* wqb  = ob + 4 * SEG;
        bf16* wkb  = ob + 5 * SEG;
        bf16* wvb  = ob + 6 * SEG;
        bf16* wob  = ob + 7 * SEG;
        bf16* qws  = ob + 8 * SEG;
        bf16* kws  = qws + elems;
        bf16* vtws = kws + elems;
        bf16* aws  = xb;                        // alias: xb dead after QKV GEMMs

        cvt_all<<<4096, blk, 0, stream>>>(x, wq, wk, wv, wo, ob);
        gemm_qkv_b<<<dim3(32, 8, 3), blk, 0, stream>>>(xb, wqb, wkb, wvb,
                                                       qws, kws, vtws);
        attn_fwd<<<dim3(NBATCH * NH, 32), dim3(512), 0, stream>>>(qws, kws, vtws, aws);
        gemm_o_b<<<dim3(32, 16), blk, 0, stream>>>(aws, wob, out);
    } else {
        if (ws_size < elems * 4 * sizeof(bf16)) return;
        bf16* qws  = (bf16*)d_ws;
        bf16* kws  = qws + elems;
        bf16* vtws = kws + elems;
        bf16* aws  = vtws + elems;

        gemm_qkv_f32<<<dim3(32, 8, 3), blk, 0, stream>>>(x, wq, wk, wv,
                                                         qws, kws, vtws);
        attn_fwd<<<dim3(NBATCH * NH, 32), dim3(512), 0, stream>>>(qws, kws, vtws, aws);
        gemm_o_f32<<<dim3(32, 16), blk, 0, stream>>>(aws, wo, out);
    }
}